// Round 1
// baseline (1245.968 us; speedup 1.0000x reference)
//
#include <hip/hip_runtime.h>
#include <cstdint>

// Problem constants (fixed by reference)
#define NTOK 32768
#define DDIM 256
#define KCB  4096

// Tiling
#define TM 128        // tokens per block
#define TN 128        // codewords per k-tile
#define DC 32         // D chunk
#define LS 132        // LDS row stride in floats (128 + 4 pad, keeps 16B alignment)
#define KSPLIT 4
#define KPER (KCB / KSPLIT)   // 1024 codewords per block

// ---------------------------------------------------------------------------
// e2[k] = sum_d embed[k][d]^2
// ---------------------------------------------------------------------------
__global__ __launch_bounds__(256) void vq_e2_kernel(const float* __restrict__ embed,
                                                    float* __restrict__ e2) {
    int k = blockIdx.x * blockDim.x + threadIdx.x;
    if (k >= KCB) return;
    const float4* row = (const float4*)(embed + (size_t)k * DDIM);
    float s = 0.f;
#pragma unroll
    for (int i = 0; i < DDIM / 4; ++i) {
        float4 v = row[i];
        s += v.x * v.x + v.y * v.y + v.z * v.z + v.w * v.w;
    }
    e2[k] = s;
}

// ---------------------------------------------------------------------------
// Main: fused GEMM (x . embed^T) + running argmin of (e2 - 2*xe) per token.
// Grid: (NTOK/TM, KSPLIT). Each block: TM tokens x KPER codewords.
// ---------------------------------------------------------------------------
__global__ __launch_bounds__(256, 3) void vq_main_kernel(
        const float* __restrict__ x, const float* __restrict__ embed,
        const float* __restrict__ e2,
        float* __restrict__ bestv, int* __restrict__ besti) {
    __shared__ union U {
        struct { float xs[DC][LS]; float es[DC][LS]; } t;   // transposed tiles [d][m]/[d][k]
        struct { float v[TM][16]; int i[TM][16]; } r;       // final reduction
    } sh;

    const int tid = threadIdx.x;
    const int tx = tid & 15;      // col group: cols tx*4+{0..3} and +64
    const int ty = tid >> 4;      // row group: rows ty*4+{0..3} and +64
    const int m0 = blockIdx.x * TM;
    const int kbase = blockIdx.y * KPER;

    // staging mapping: thread loads one float4 per pass
    const int srow = tid >> 3;          // 0..31
    const int sd4  = (tid & 7) * 4;     // 0,4,...,28

    float bv[2][4];
    int   bi[2][4];
#pragma unroll
    for (int a = 0; a < 2; ++a)
#pragma unroll
        for (int b = 0; b < 4; ++b) { bv[a][b] = 3.4e38f; bi[a][b] = 0; }

    for (int kt = 0; kt < KPER / TN; ++kt) {
        const int k0 = kbase + kt * TN;
        float acc[2][4][2][4];
#pragma unroll
        for (int a = 0; a < 2; ++a)
#pragma unroll
            for (int b = 0; b < 4; ++b)
#pragma unroll
                for (int c = 0; c < 2; ++c)
#pragma unroll
                    for (int e = 0; e < 4; ++e) acc[a][b][c][e] = 0.f;

        for (int dc = 0; dc < DDIM / DC; ++dc) {
            // stage x tile and e tile transposed into LDS
#pragma unroll
            for (int p = 0; p < 4; ++p) {
                int m = p * 32 + srow;
                float4 v = *(const float4*)(x + (size_t)(m0 + m) * DDIM + dc * DC + sd4);
                sh.t.xs[sd4 + 0][m] = v.x;
                sh.t.xs[sd4 + 1][m] = v.y;
                sh.t.xs[sd4 + 2][m] = v.z;
                sh.t.xs[sd4 + 3][m] = v.w;
                float4 w = *(const float4*)(embed + (size_t)(k0 + m) * DDIM + dc * DC + sd4);
                sh.t.es[sd4 + 0][m] = w.x;
                sh.t.es[sd4 + 1][m] = w.y;
                sh.t.es[sd4 + 2][m] = w.z;
                sh.t.es[sd4 + 3][m] = w.w;
            }
            __syncthreads();
#pragma unroll 8
            for (int d = 0; d < DC; ++d) {
                float4 xa0 = *(const float4*)&sh.t.xs[d][ty * 4];
                float4 xa1 = *(const float4*)&sh.t.xs[d][ty * 4 + 64];
                float4 eb0 = *(const float4*)&sh.t.es[d][tx * 4];
                float4 eb1 = *(const float4*)&sh.t.es[d][tx * 4 + 64];
                float xr[2][4] = {{xa0.x, xa0.y, xa0.z, xa0.w},
                                  {xa1.x, xa1.y, xa1.z, xa1.w}};
                float er[2][4] = {{eb0.x, eb0.y, eb0.z, eb0.w},
                                  {eb1.x, eb1.y, eb1.z, eb1.w}};
#pragma unroll
                for (int a = 0; a < 2; ++a)
#pragma unroll
                    for (int b = 0; b < 4; ++b)
#pragma unroll
                        for (int c = 0; c < 2; ++c)
#pragma unroll
                            for (int e = 0; e < 4; ++e)
                                acc[a][b][c][e] += xr[a][b] * er[c][e];
            }
            __syncthreads();
        }
        // score epilogue: s = e2[k] - 2*dot; ascending k within thread, strict <
#pragma unroll
        for (int c = 0; c < 2; ++c)
#pragma unroll
            for (int e = 0; e < 4; ++e) {
                int k = k0 + c * 64 + tx * 4 + e;
                float ek = e2[k];
#pragma unroll
                for (int a = 0; a < 2; ++a)
#pragma unroll
                    for (int b = 0; b < 4; ++b) {
                        float s = ek - 2.f * acc[a][b][c][e];
                        if (s < bv[a][b]) { bv[a][b] = s; bi[a][b] = k; }
                    }
            }
    }

    // cross-thread (tx) reduction per token row
    __syncthreads();
#pragma unroll
    for (int a = 0; a < 2; ++a)
#pragma unroll
        for (int b = 0; b < 4; ++b) {
            int row = a * 64 + ty * 4 + b;
            sh.r.v[row][tx] = bv[a][b];
            sh.r.i[row][tx] = bi[a][b];
        }
    __syncthreads();
    if (tid < TM) {
        float best = sh.r.v[tid][0];
        int idx = sh.r.i[tid][0];
#pragma unroll
        for (int j = 1; j < 16; ++j) {
            float v = sh.r.v[tid][j];
            int ii = sh.r.i[tid][j];
            if (v < best || (v == best && ii < idx)) { best = v; idx = ii; }
        }
        bestv[(size_t)blockIdx.y * NTOK + m0 + tid] = best;
        besti[(size_t)blockIdx.y * NTOK + m0 + tid] = idx;
    }
}

// ---------------------------------------------------------------------------
// Merge K-splits and gather codebook rows: out[n][:] = embed[argmin][:]
// Block 256 = 4 tokens x 64 lanes; 64 lanes x float4 = 256 floats per row.
// ---------------------------------------------------------------------------
__global__ __launch_bounds__(256) void vq_gather_kernel(
        const float* __restrict__ embed, const float* __restrict__ bestv,
        const int* __restrict__ besti, float* __restrict__ out) {
    int token = blockIdx.x * 4 + (threadIdx.x >> 6);
    int lane = threadIdx.x & 63;
    float best = bestv[token];
    int idx = besti[token];
#pragma unroll
    for (int s = 1; s < KSPLIT; ++s) {
        float v = bestv[(size_t)s * NTOK + token];
        int ii = besti[(size_t)s * NTOK + token];
        if (v < best || (v == best && ii < idx)) { best = v; idx = ii; }
    }
    const float4* src = (const float4*)(embed + (size_t)idx * DDIM);
    float4* dst = (float4*)(out + (size_t)token * DDIM);
    dst[lane] = src[lane];
}

extern "C" void kernel_launch(void* const* d_in, const int* in_sizes, int n_in,
                              void* d_out, int out_size, void* d_ws, size_t ws_size,
                              hipStream_t stream) {
    (void)in_sizes; (void)n_in; (void)out_size; (void)ws_size;
    const float* x = (const float*)d_in[0];      // [1, 32768, 256] fp32
    const float* embed = (const float*)d_in[1];  // [1, 4096, 256] fp32
    float* out = (float*)d_out;                  // [1, 32768, 256] fp32

    float* e2 = (float*)d_ws;                    // [4096]
    float* bestv = e2 + KCB;                     // [KSPLIT][NTOK]
    int* besti = (int*)(bestv + (size_t)KSPLIT * NTOK);  // [KSPLIT][NTOK]

    vq_e2_kernel<<<KCB / 256, 256, 0, stream>>>(embed, e2);
    vq_main_kernel<<<dim3(NTOK / TM, KSPLIT), 256, 0, stream>>>(x, embed, e2, bestv, besti);
    vq_gather_kernel<<<NTOK / 4, 256, 0, stream>>>(embed, bestv, besti, out);
}

// Round 2
// 569.984 us; speedup vs baseline: 2.1860x; 2.1860x over previous
//
#include <hip/hip_runtime.h>
#include <cstdint>

#define NTOK 32768
#define DDIM 256
#define KCB  4096
#define MARGIN 0.05f

typedef short bf16x8 __attribute__((ext_vector_type(8)));
typedef float f32x4 __attribute__((ext_vector_type(4)));
typedef unsigned short ushort_t;

// ---------------------------------------------------------------------------
// helpers
// ---------------------------------------------------------------------------
__device__ __forceinline__ ushort_t f2bf(float f) {
    unsigned u = __float_as_uint(f);
    unsigned r = (u + 0x7fffu + ((u >> 16) & 1u)) >> 16;
    return (ushort_t)r;
}
__device__ __forceinline__ float bf2f(ushort_t h) {
    return __uint_as_float(((unsigned)h) << 16);
}
__device__ __forceinline__ void gload_lds16(const void* g, void* l) {
    __builtin_amdgcn_global_load_lds(
        (const __attribute__((address_space(1))) void*)g,
        (__attribute__((address_space(3))) void*)l, 16, 0, 0);
}

// ---------------------------------------------------------------------------
// convert fp32 -> bf16 hi + bf16 lo (residual), 1 float4 per thread
// ---------------------------------------------------------------------------
__global__ __launch_bounds__(256) void vq_convert_kernel(
        const float* __restrict__ src, ushort_t* __restrict__ hi,
        ushort_t* __restrict__ lo, int n4) {
    int i = blockIdx.x * 256 + threadIdx.x;
    if (i >= n4) return;
    float4 v = ((const float4*)src)[i];
    ushort4 h, l;
    h.x = f2bf(v.x); l.x = f2bf(v.x - bf2f(h.x));
    h.y = f2bf(v.y); l.y = f2bf(v.y - bf2f(h.y));
    h.z = f2bf(v.z); l.z = f2bf(v.z - bf2f(h.z));
    h.w = f2bf(v.w); l.w = f2bf(v.w - bf2f(h.w));
    ((ushort4*)hi)[i] = h;
    ((ushort4*)lo)[i] = l;
}

// ---------------------------------------------------------------------------
// e2[k] = sum_d embed[k][d]^2 (fp32)
// ---------------------------------------------------------------------------
__global__ __launch_bounds__(256) void vq_e2_kernel(const float* __restrict__ embed,
                                                    float* __restrict__ e2) {
    int k = blockIdx.x * blockDim.x + threadIdx.x;
    if (k >= KCB) return;
    const float4* row = (const float4*)(embed + (size_t)k * DDIM);
    float s = 0.f;
#pragma unroll
    for (int i = 0; i < DDIM / 4; ++i) {
        float4 v = row[i];
        s += v.x * v.x + v.y * v.y + v.z * v.z + v.w * v.w;
    }
    e2[k] = s;
}

// ---------------------------------------------------------------------------
// Pass A: bf16 MFMA GEMM-argmin. dot = xh.eh + xh.el + xl.eh  (K=768 virtual)
// Block 128x128, 4 waves (2x2), each wave 4x4 tiles of 16x16x32.
// Outputs per (token, nblock): best (v1,i1) and second-best value v2.
// ---------------------------------------------------------------------------
__global__ __launch_bounds__(256) void vq_mfma_kernel(
        const ushort_t* __restrict__ xh, const ushort_t* __restrict__ xl,
        const ushort_t* __restrict__ eh, const ushort_t* __restrict__ el,
        const float* __restrict__ e2,
        float* __restrict__ gv1, int* __restrict__ gi1, float* __restrict__ gv2) {
    __shared__ union U {
        struct { short A[128 * 32]; short B[128 * 32]; } t;  // 16 KB tiles (bf16)
        struct { float v1[128][2]; int i1[128][2]; float v2[128][2]; } r;
    } sh;

    const int tid = threadIdx.x;
    const int m0 = blockIdx.x * 128;
    const int n0 = blockIdx.y * 128;

    // ---- staging mapping: 512 chunks of 16B per tile, 2 per thread ----
    // physical chunk c: row = c>>2, phys-quad = c&3; global quad = pq ^ (row&3)
    const int ca0 = tid, ca1 = 256 + tid;
    const int row0 = ca0 >> 2, gq0 = (ca0 & 3) ^ (row0 & 3);
    const int row1 = ca1 >> 2, gq1 = (ca1 & 3) ^ (row1 & 3);
    const size_t aoff0 = (size_t)(m0 + row0) * DDIM + gq0 * 8;
    const size_t aoff1 = (size_t)(m0 + row1) * DDIM + gq1 * 8;
    const size_t boff0 = (size_t)(n0 + row0) * DDIM + gq0 * 8;
    const size_t boff1 = (size_t)(n0 + row1) * DDIM + gq1 * 8;
    short* lA0 = &sh.t.A[ca0 * 8]; short* lA1 = &sh.t.A[ca1 * 8];
    short* lB0 = &sh.t.B[ca0 * 8]; short* lB1 = &sh.t.B[ca1 * 8];

    // ---- fragment read mapping ----
    const int lane = tid & 63;
    const int wv = tid >> 6;          // wave 0..3
    const int wr = wv >> 1, wc = wv & 1;
    const int L15 = lane & 15, quad = lane >> 4;
    const int pqf = quad ^ (L15 & 3);      // swizzled physical quad
    const char* Abase = (const char*)sh.t.A + (size_t)(wr * 64 + L15) * 64 + pqf * 16;
    const char* Bbase = (const char*)sh.t.B + (size_t)(wc * 64 + L15) * 64 + pqf * 16;

    f32x4 acc[4][4];
#pragma unroll
    for (int i = 0; i < 4; ++i)
#pragma unroll
        for (int j = 0; j < 4; ++j) acc[i][j] = (f32x4){0.f, 0.f, 0.f, 0.f};

#pragma unroll 1
    for (int p = 0; p < 3; ++p) {
        const ushort_t* Ag = (p < 2) ? xh : xl;   // hi.hi, hi.lo, lo.hi
        const ushort_t* Bg = (p == 1) ? el : eh;
        const ushort_t* a0 = Ag + aoff0; const ushort_t* a1 = Ag + aoff1;
        const ushort_t* b0 = Bg + boff0; const ushort_t* b1 = Bg + boff1;
#pragma unroll 1
        for (int kk = 0; kk < 8; ++kk) {
            gload_lds16(a0 + kk * 32, lA0);
            gload_lds16(a1 + kk * 32, lA1);
            gload_lds16(b0 + kk * 32, lB0);
            gload_lds16(b1 + kk * 32, lB1);
            __syncthreads();
            bf16x8 af[4], bfj[4];
#pragma unroll
            for (int i = 0; i < 4; ++i) af[i] = *(const bf16x8*)(Abase + i * 1024);
#pragma unroll
            for (int j = 0; j < 4; ++j) bfj[j] = *(const bf16x8*)(Bbase + j * 1024);
#pragma unroll
            for (int i = 0; i < 4; ++i)
#pragma unroll
                for (int j = 0; j < 4; ++j)
                    acc[i][j] = __builtin_amdgcn_mfma_f32_16x16x32_bf16(
                        af[i], bfj[j], acc[i][j], 0, 0, 0);
            __syncthreads();
        }
    }

    // ---- epilogue: s = e2[n] - 2*dot; per-row top-2 (value,index) ----
    float e2v[4];
#pragma unroll
    for (int j = 0; j < 4; ++j) e2v[j] = e2[n0 + wc * 64 + j * 16 + L15];

#pragma unroll
    for (int i = 0; i < 4; ++i) {
#pragma unroll
        for (int r = 0; r < 4; ++r) {
            float v1 = 3.4e38f, v2 = 3.4e38f; int i1 = 0;
#pragma unroll
            for (int j = 0; j < 4; ++j) {
                float s = e2v[j] - 2.f * acc[i][j][r];
                int n = n0 + wc * 64 + j * 16 + L15;
                if (s < v1) { v2 = v1; v1 = s; i1 = n; }
                else if (s < v2) { v2 = s; }
            }
            // butterfly over the 16 lanes holding this row
#pragma unroll
            for (int off = 1; off < 16; off <<= 1) {
                float ov1 = __shfl_xor(v1, off, 64);
                int   oi1 = __shfl_xor(i1, off, 64);
                float ov2 = __shfl_xor(v2, off, 64);
                if (ov1 < v1 || (ov1 == v1 && oi1 < i1)) {
                    v2 = fminf(v1, ov2); v1 = ov1; i1 = oi1;
                } else {
                    v2 = fminf(v2, ov1);
                }
            }
            if (L15 == 0) {
                int lr = wr * 64 + i * 16 + quad * 4 + r;
                sh.r.v1[lr][wc] = v1; sh.r.i1[lr][wc] = i1; sh.r.v2[lr][wc] = v2;
            }
        }
    }
    __syncthreads();
    if (tid < 128) {
        float av1 = sh.r.v1[tid][0]; int ai1 = sh.r.i1[tid][0]; float av2 = sh.r.v2[tid][0];
        float bv1 = sh.r.v1[tid][1]; int bi1 = sh.r.i1[tid][1]; float bv2 = sh.r.v2[tid][1];
        float v1, v2; int i1;
        if (bv1 < av1 || (bv1 == av1 && bi1 < ai1)) { v1 = bv1; i1 = bi1; v2 = fminf(av1, bv2); }
        else { v1 = av1; i1 = ai1; v2 = fminf(av2, bv1); }
        size_t o = (size_t)(m0 + tid) * 32 + blockIdx.y;
        gv1[o] = v1; gi1[o] = i1; gv2[o] = v2;
    }
}

// ---------------------------------------------------------------------------
// merge 32 n-blocks per token; flag small-gap tokens for fp32 rescore
// ---------------------------------------------------------------------------
__global__ __launch_bounds__(256) void vq_merge_kernel(
        const float* __restrict__ gv1, const int* __restrict__ gi1,
        const float* __restrict__ gv2, int* __restrict__ idx_final,
        int* __restrict__ worklist, int* __restrict__ count) {
    int t = blockIdx.x * 256 + threadIdx.x;
    if (t >= NTOK) return;
    float v1 = 3.4e38f, v2 = 3.4e38f; int i1 = 0x7fffffff;
#pragma unroll
    for (int nb = 0; nb < 32; ++nb) {
        size_t o = (size_t)t * 32 + nb;
        float a1 = gv1[o]; int ai = gi1[o]; float a2 = gv2[o];
        if (a1 < v1 || (a1 == v1 && ai < i1)) {
            v2 = fminf(v1, a2); v1 = a1; i1 = ai;
        } else {
            v2 = fminf(v2, a1);
        }
    }
    idx_final[t] = i1;
    if (v2 - v1 < MARGIN) {
        int p = atomicAdd(count, 1);
        worklist[p] = t;
    }
}

// ---------------------------------------------------------------------------
// Pass B: exact fp32 full-scan rescore for flagged tokens (1 block / token)
// ---------------------------------------------------------------------------
__global__ __launch_bounds__(256) void vq_rescore_kernel(
        const float* __restrict__ x, const float* __restrict__ embed,
        const float* __restrict__ e2, const int* __restrict__ worklist,
        const int* __restrict__ count, int* __restrict__ idx_final) {
    __shared__ float xs[DDIM];
    __shared__ float rv[256];
    __shared__ int ri[256];
    const int tid = threadIdx.x;
    const int cnt = *count;
    for (int wi = blockIdx.x; wi < cnt; wi += gridDim.x) {
        int t = worklist[wi];
        __syncthreads();
        xs[tid] = x[(size_t)t * DDIM + tid];
        __syncthreads();
        float bv = 3.4e38f; int bi = 0;
        const float4* xv = (const float4*)xs;
#pragma unroll 1
        for (int g = 0; g < 16; ++g) {
            int n = tid * 16 + g;   // contiguous chunk -> ascending-index tie-break
            const float4* er = (const float4*)(embed + (size_t)n * DDIM);
            float acc = 0.f;
#pragma unroll 8
            for (int d4 = 0; d4 < DDIM / 4; ++d4) {
                float4 e = er[d4]; float4 xx = xv[d4];
                acc += e.x * xx.x + e.y * xx.y + e.z * xx.z + e.w * xx.w;
            }
            float s = e2[n] - 2.f * acc;
            if (s < bv) { bv = s; bi = n; }
        }
        rv[tid] = bv; ri[tid] = bi;
        __syncthreads();
        for (int s2 = 128; s2 > 0; s2 >>= 1) {
            if (tid < s2) {
                float ov = rv[tid + s2]; int oi = ri[tid + s2];
                if (ov < rv[tid] || (ov == rv[tid] && oi < ri[tid])) {
                    rv[tid] = ov; ri[tid] = oi;
                }
            }
            __syncthreads();
        }
        if (tid == 0) idx_final[t] = ri[0];
    }
}

// ---------------------------------------------------------------------------
// gather: out[t][:] = embed[idx_final[t]][:]
// ---------------------------------------------------------------------------
__global__ __launch_bounds__(256) void vq_gather2_kernel(
        const float* __restrict__ embed, const int* __restrict__ idx_final,
        float* __restrict__ out) {
    int token = blockIdx.x * 4 + (threadIdx.x >> 6);
    int lane = threadIdx.x & 63;
    int idx = idx_final[token];
    const float4* src = (const float4*)(embed + (size_t)idx * DDIM);
    float4* dst = (float4*)(out + (size_t)token * DDIM);
    dst[lane] = src[lane];
}

// ===========================================================================
// Fallback fp32 path (round-1 kernels) for small workspace
// ===========================================================================
#define TMF 128
#define DCF 32
#define LSF 132
#define KSPLITF 4
#define KPERF (KCB / KSPLITF)

__global__ __launch_bounds__(256, 3) void vq_main_fp32(
        const float* __restrict__ x, const float* __restrict__ embed,
        const float* __restrict__ e2,
        float* __restrict__ bestv, int* __restrict__ besti) {
    __shared__ union U {
        struct { float xs[DCF][LSF]; float es[DCF][LSF]; } t;
        struct { float v[TMF][16]; int i[TMF][16]; } r;
    } sh;
    const int tid = threadIdx.x;
    const int tx = tid & 15, ty = tid >> 4;
    const int m0 = blockIdx.x * TMF;
    const int kbase = blockIdx.y * KPERF;
    const int srow = tid >> 3, sd4 = (tid & 7) * 4;
    float bv[2][4]; int bi[2][4];
#pragma unroll
    for (int a = 0; a < 2; ++a)
#pragma unroll
        for (int b = 0; b < 4; ++b) { bv[a][b] = 3.4e38f; bi[a][b] = 0; }
    for (int kt = 0; kt < KPERF / 128; ++kt) {
        const int k0 = kbase + kt * 128;
        float acc[2][4][2][4];
#pragma unroll
        for (int a = 0; a < 2; ++a)
#pragma unroll
            for (int b = 0; b < 4; ++b)
#pragma unroll
                for (int c = 0; c < 2; ++c)
#pragma unroll
                    for (int e = 0; e < 4; ++e) acc[a][b][c][e] = 0.f;
        for (int dc = 0; dc < DDIM / DCF; ++dc) {
#pragma unroll
            for (int p = 0; p < 4; ++p) {
                int m = p * 32 + srow;
                float4 v = *(const float4*)(x + (size_t)(m0 + m) * DDIM + dc * DCF + sd4);
                sh.t.xs[sd4 + 0][m] = v.x; sh.t.xs[sd4 + 1][m] = v.y;
                sh.t.xs[sd4 + 2][m] = v.z; sh.t.xs[sd4 + 3][m] = v.w;
                float4 w = *(const float4*)(embed + (size_t)(k0 + m) * DDIM + dc * DCF + sd4);
                sh.t.es[sd4 + 0][m] = w.x; sh.t.es[sd4 + 1][m] = w.y;
                sh.t.es[sd4 + 2][m] = w.z; sh.t.es[sd4 + 3][m] = w.w;
            }
            __syncthreads();
#pragma unroll 8
            for (int d = 0; d < DCF; ++d) {
                float4 xa0 = *(const float4*)&sh.t.xs[d][ty * 4];
                float4 xa1 = *(const float4*)&sh.t.xs[d][ty * 4 + 64];
                float4 eb0 = *(const float4*)&sh.t.es[d][tx * 4];
                float4 eb1 = *(const float4*)&sh.t.es[d][tx * 4 + 64];
                float xr[2][4] = {{xa0.x, xa0.y, xa0.z, xa0.w}, {xa1.x, xa1.y, xa1.z, xa1.w}};
                float er[2][4] = {{eb0.x, eb0.y, eb0.z, eb0.w}, {eb1.x, eb1.y, eb1.z, eb1.w}};
#pragma unroll
                for (int a = 0; a < 2; ++a)
#pragma unroll
                    for (int b = 0; b < 4; ++b)
#pragma unroll
                        for (int c = 0; c < 2; ++c)
#pragma unroll
                            for (int e = 0; e < 4; ++e)
                                acc[a][b][c][e] += xr[a][b] * er[c][e];
            }
            __syncthreads();
        }
#pragma unroll
        for (int c = 0; c < 2; ++c)
#pragma unroll
            for (int e = 0; e < 4; ++e) {
                int k = k0 + c * 64 + tx * 4 + e;
                float ek = e2[k];
#pragma unroll
                for (int a = 0; a < 2; ++a)
#pragma unroll
                    for (int b = 0; b < 4; ++b) {
                        float s = ek - 2.f * acc[a][b][c][e];
                        if (s < bv[a][b]) { bv[a][b] = s; bi[a][b] = k; }
                    }
            }
    }
    __syncthreads();
#pragma unroll
    for (int a = 0; a < 2; ++a)
#pragma unroll
        for (int b = 0; b < 4; ++b) {
            int row = a * 64 + ty * 4 + b;
            sh.r.v[row][tx] = bv[a][b]; sh.r.i[row][tx] = bi[a][b];
        }
    __syncthreads();
    if (tid < TMF) {
        float best = sh.r.v[tid][0]; int idx = sh.r.i[tid][0];
#pragma unroll
        for (int j = 1; j < 16; ++j) {
            float v = sh.r.v[tid][j]; int ii = sh.r.i[tid][j];
            if (v < best || (v == best && ii < idx)) { best = v; idx = ii; }
        }
        bestv[(size_t)blockIdx.y * NTOK + m0 + tid] = best;
        besti[(size_t)blockIdx.y * NTOK + m0 + tid] = idx;
    }
}

__global__ __launch_bounds__(256) void vq_gather_fp32(
        const float* __restrict__ embed, const float* __restrict__ bestv,
        const int* __restrict__ besti, float* __restrict__ out) {
    int token = blockIdx.x * 4 + (threadIdx.x >> 6);
    int lane = threadIdx.x & 63;
    float best = bestv[token]; int idx = besti[token];
#pragma unroll
    for (int s = 1; s < KSPLITF; ++s) {
        float v = bestv[(size_t)s * NTOK + token];
        int ii = besti[(size_t)s * NTOK + token];
        if (v < best || (v == best && ii < idx)) { best = v; idx = ii; }
    }
    const float4* src = (const float4*)(embed + (size_t)idx * DDIM);
    float4* dst = (float4*)(out + (size_t)token * DDIM);
    dst[lane] = src[lane];
}

// ===========================================================================
extern "C" void kernel_launch(void* const* d_in, const int* in_sizes, int n_in,
                              void* d_out, int out_size, void* d_ws, size_t ws_size,
                              hipStream_t stream) {
    (void)in_sizes; (void)n_in; (void)out_size;
    const float* x = (const float*)d_in[0];
    const float* embed = (const float*)d_in[1];
    float* out = (float*)d_out;

    char* w = (char*)d_ws;
    auto carve = [&](size_t bytes) { char* p = w; w += (bytes + 255) & ~(size_t)255; return p; };

    const size_t sz_xh = (size_t)NTOK * DDIM * 2;
    const size_t sz_eh = (size_t)KCB * DDIM * 2;
    const size_t need = 2 * sz_xh + 2 * sz_eh + KCB * 4 + 3 * (size_t)NTOK * 32 * 4 +
                        (size_t)NTOK * 4 * 2 + 4096;

    if (ws_size >= need) {
        ushort_t* xh = (ushort_t*)carve(sz_xh);
        ushort_t* xl = (ushort_t*)carve(sz_xh);
        ushort_t* eh = (ushort_t*)carve(sz_eh);
        ushort_t* el = (ushort_t*)carve(sz_eh);
        float* e2 = (float*)carve(KCB * 4);
        float* gv1 = (float*)carve((size_t)NTOK * 32 * 4);
        int* gi1 = (int*)carve((size_t)NTOK * 32 * 4);
        float* gv2 = (float*)carve((size_t)NTOK * 32 * 4);
        int* idx_final = (int*)carve((size_t)NTOK * 4);
        int* worklist = (int*)carve((size_t)NTOK * 4);
        int* count = (int*)carve(256);

        vq_convert_kernel<<<(NTOK * DDIM / 4 + 255) / 256, 256, 0, stream>>>(x, xh, xl, NTOK * DDIM / 4);
        vq_convert_kernel<<<(KCB * DDIM / 4 + 255) / 256, 256, 0, stream>>>(embed, eh, el, KCB * DDIM / 4);
        vq_e2_kernel<<<KCB / 256, 256, 0, stream>>>(embed, e2);
        hipMemsetAsync(count, 0, 4, stream);
        vq_mfma_kernel<<<dim3(NTOK / 128, KCB / 128), 256, 0, stream>>>(
            xh, xl, eh, el, e2, gv1, gi1, gv2);
        vq_merge_kernel<<<NTOK / 256, 256, 0, stream>>>(gv1, gi1, gv2, idx_final, worklist, count);
        vq_rescore_kernel<<<1024, 256, 0, stream>>>(x, embed, e2, worklist, count, idx_final);
        vq_gather2_kernel<<<NTOK / 4, 256, 0, stream>>>(embed, idx_final, out);
    } else {
        float* e2 = (float*)carve(KCB * 4);
        float* bestv = (float*)carve((size_t)KSPLITF * NTOK * 4);
        int* besti = (int*)carve((size_t)KSPLITF * NTOK * 4);
        vq_e2_kernel<<<KCB / 256, 256, 0, stream>>>(embed, e2);
        vq_main_fp32<<<dim3(NTOK / TMF, KSPLITF), 256, 0, stream>>>(x, embed, e2, bestv, besti);
        vq_gather_fp32<<<NTOK / 4, 256, 0, stream>>>(embed, bestv, besti, out);
    }
}

// Round 3
// 281.876 us; speedup vs baseline: 4.4203x; 2.0221x over previous
//
#include <hip/hip_runtime.h>
#include <cstdint>

#define NTOK 32768
#define DDIM 256
#define KCB  4096
#define MARGIN1 0.30f
#define NSA 4      // n-splits in pass A (1024 codes per block)
#define NST 16     // n-splits in tier-2 (256 codes per block)

typedef _Float16 half8 __attribute__((ext_vector_type(8)));
typedef float f32x4 __attribute__((ext_vector_type(4)));
typedef unsigned short ushort_t;

// ---------------------------------------------------------------------------
// helpers
// ---------------------------------------------------------------------------
__device__ __forceinline__ ushort_t f2h(float f, float& back) {
    _Float16 h = (_Float16)f;
    back = (float)h;
    union { _Float16 h; ushort_t u; } c; c.h = h; return c.u;
}
__device__ __forceinline__ void gload_lds16(const void* g, void* l) {
    __builtin_amdgcn_global_load_lds(
        (const __attribute__((address_space(1))) void*)g,
        (__attribute__((address_space(3))) void*)l, 16, 0, 0);
}
__device__ __forceinline__ void stage4(const ushort_t* a0, const ushort_t* a1,
                                       const ushort_t* b0, const ushort_t* b1,
                                       short* lA0, short* lA1, short* lB0, short* lB1,
                                       int koff) {
    gload_lds16(a0 + koff, lA0);
    gload_lds16(a1 + koff, lA1);
    gload_lds16(b0 + koff, lB0);
    gload_lds16(b1 + koff, lB1);
}
template <bool FIRST>
__device__ __forceinline__ void frag_mfma(const char* Ab, const char* Bb, f32x4 (&acc)[4][4]) {
    half8 af[4], bf[4];
#pragma unroll
    for (int i = 0; i < 4; ++i) af[i] = *(const half8*)(Ab + i * 1024);
#pragma unroll
    for (int j = 0; j < 4; ++j) bf[j] = *(const half8*)(Bb + j * 1024);
#pragma unroll
    for (int i = 0; i < 4; ++i)
#pragma unroll
        for (int j = 0; j < 4; ++j) {
            if (FIRST)
                acc[i][j] = __builtin_amdgcn_mfma_f32_16x16x32_f16(
                    af[i], bf[j], (f32x4){0.f, 0.f, 0.f, 0.f}, 0, 0, 0);
            else
                acc[i][j] = __builtin_amdgcn_mfma_f32_16x16x32_f16(
                    af[i], bf[j], acc[i][j], 0, 0, 0);
        }
}

// ---------------------------------------------------------------------------
// convert x: fp32 -> f16 hi + f16 lo(residual)
// ---------------------------------------------------------------------------
__global__ __launch_bounds__(256) void vq_convert_x(
        const float* __restrict__ src, ushort_t* __restrict__ hi,
        ushort_t* __restrict__ lo) {
    int i = blockIdx.x * 256 + threadIdx.x;          // one float4 per thread
    float4 v = ((const float4*)src)[i];
    float bx, by, bz, bw;
    ushort4 h, l;
    h.x = f2h(v.x, bx); h.y = f2h(v.y, by); h.z = f2h(v.z, bz); h.w = f2h(v.w, bw);
    float t;
    l.x = f2h(v.x - bx, t); l.y = f2h(v.y - by, t);
    l.z = f2h(v.z - bz, t); l.w = f2h(v.w - bw, t);
    ((ushort4*)hi)[i] = h;
    ((ushort4*)lo)[i] = l;
}

// ---------------------------------------------------------------------------
// convert embed (wave per row) + e2 row-sum-of-squares (fp32)
// ---------------------------------------------------------------------------
__global__ __launch_bounds__(256) void vq_convert_e(
        const float* __restrict__ embed, ushort_t* __restrict__ hi,
        ushort_t* __restrict__ lo, float* __restrict__ e2) {
    int row = blockIdx.x * 4 + (threadIdx.x >> 6);
    int lane = threadIdx.x & 63;
    size_t off = (size_t)row * DDIM + lane * 4;
    float4 v = *(const float4*)(embed + off);
    float bx, by, bz, bw;
    ushort4 h, l;
    h.x = f2h(v.x, bx); h.y = f2h(v.y, by); h.z = f2h(v.z, bz); h.w = f2h(v.w, bw);
    float t;
    l.x = f2h(v.x - bx, t); l.y = f2h(v.y - by, t);
    l.z = f2h(v.z - bz, t); l.w = f2h(v.w - bw, t);
    *(ushort4*)(hi + off) = h;
    *(ushort4*)(lo + off) = l;
    float s = v.x * v.x + v.y * v.y + v.z * v.z + v.w * v.w;
#pragma unroll
    for (int o = 1; o < 64; o <<= 1) s += __shfl_xor(s, o, 64);
    if (lane == 0) e2[row] = s;
}

// ---------------------------------------------------------------------------
// Pass A: 1-pass f16 GEMM-argmin, 128 tokens x 1024 codes per block,
// 8 n-tiles x 8 k-iters, running per-lane top-2, one butterfly at the end.
// ---------------------------------------------------------------------------
__global__ __launch_bounds__(256, 2) void vq_pass_a(
        const ushort_t* __restrict__ xh, const ushort_t* __restrict__ eh,
        const float* __restrict__ e2,
        float* __restrict__ gv1, int* __restrict__ gi1, float* __restrict__ gv2) {
    __shared__ union U {
        struct { short A[128 * 32]; short B[128 * 32]; } t;
        struct { float v1[128][2]; int i1[128][2]; float v2[128][2]; } r;
    } sh;
    const int tid = threadIdx.x;
    const int m0 = blockIdx.x * 128;
    const int kbase = blockIdx.y * (KCB / NSA);

    const int ca0 = tid, ca1 = 256 + tid;
    const int row0 = ca0 >> 2, gq0 = (ca0 & 3) ^ (row0 & 3);
    const int row1 = ca1 >> 2, gq1 = (ca1 & 3) ^ (row1 & 3);
    short* lA0 = &sh.t.A[ca0 * 8]; short* lA1 = &sh.t.A[ca1 * 8];
    short* lB0 = &sh.t.B[ca0 * 8]; short* lB1 = &sh.t.B[ca1 * 8];
    const ushort_t* Ag0 = xh + (size_t)(m0 + row0) * DDIM + gq0 * 8;
    const ushort_t* Ag1 = xh + (size_t)(m0 + row1) * DDIM + gq1 * 8;

    const int lane = tid & 63, wv = tid >> 6, wr = wv >> 1, wc = wv & 1;
    const int L15 = lane & 15, quad = lane >> 4;
    const int pqf = quad ^ (L15 & 3);
    const char* Abase = (const char*)sh.t.A + (size_t)(wr * 64 + L15) * 64 + pqf * 16;
    const char* Bbase = (const char*)sh.t.B + (size_t)(wc * 64 + L15) * 64 + pqf * 16;

    float v1[16], v2[16]; int i1[16];
#pragma unroll
    for (int r2 = 0; r2 < 16; ++r2) { v1[r2] = 3.4e38f; v2[r2] = 3.4e38f; i1[r2] = 0; }

#pragma unroll 1
    for (int nt = 0; nt < (KCB / NSA) / 128; ++nt) {
        const int n0 = kbase + nt * 128;
        const ushort_t* Bg0 = eh + (size_t)(n0 + row0) * DDIM + gq0 * 8;
        const ushort_t* Bg1 = eh + (size_t)(n0 + row1) * DDIM + gq1 * 8;
        f32x4 acc[4][4];
        // kk = 0 peel (zero-C MFMA: no accvgpr zero-init)
        stage4(Ag0, Ag1, Bg0, Bg1, lA0, lA1, lB0, lB1, 0);
        __syncthreads();
        frag_mfma<true>(Abase, Bbase, acc);
        __syncthreads();
#pragma unroll 1
        for (int kk = 1; kk < 8; ++kk) {
            stage4(Ag0, Ag1, Bg0, Bg1, lA0, lA1, lB0, lB1, kk * 32);
            __syncthreads();
            frag_mfma<false>(Abase, Bbase, acc);
            __syncthreads();
        }
        // running top-2 epilogue (ascending n within lane -> strict <)
        const int nb = n0 + wc * 64 + L15;
        float e2v[4];
#pragma unroll
        for (int j = 0; j < 4; ++j) e2v[j] = e2[nb + j * 16];
#pragma unroll
        for (int i = 0; i < 4; ++i)
#pragma unroll
            for (int r = 0; r < 4; ++r) {
                const int row = i * 4 + r;
#pragma unroll
                for (int j = 0; j < 4; ++j) {
                    float s = fmaf(-2.f, acc[i][j][r], e2v[j]);
                    int n = nb + j * 16;
                    bool lt = s < v1[row];
                    v2[row] = lt ? v1[row] : fminf(v2[row], s);
                    i1[row] = lt ? n : i1[row];
                    v1[row] = lt ? s : v1[row];
                }
            }
    }
    __syncthreads();
    // cross-lane butterfly (16 lanes share a row) then cross-wc merge
#pragma unroll
    for (int row = 0; row < 16; ++row) {
        float a1 = v1[row], a2 = v2[row]; int ai = i1[row];
#pragma unroll
        for (int off = 1; off < 16; off <<= 1) {
            float o1 = __shfl_xor(a1, off, 64);
            int oi = __shfl_xor(ai, off, 64);
            float o2 = __shfl_xor(a2, off, 64);
            if (o1 < a1 || (o1 == a1 && oi < ai)) { a2 = fminf(a1, o2); a1 = o1; ai = oi; }
            else a2 = fminf(a2, o1);
        }
        if (L15 == 0) {
            int i = row >> 2, r = row & 3;
            int lr = wr * 64 + i * 16 + quad * 4 + r;
            sh.r.v1[lr][wc] = a1; sh.r.i1[lr][wc] = ai; sh.r.v2[lr][wc] = a2;
        }
    }
    __syncthreads();
    if (tid < 128) {
        float av1 = sh.r.v1[tid][0]; int ai1 = sh.r.i1[tid][0]; float av2 = sh.r.v2[tid][0];
        float bv1 = sh.r.v1[tid][1]; int bi1 = sh.r.i1[tid][1]; float bv2 = sh.r.v2[tid][1];
        float o1, o2; int oi;
        if (bv1 < av1 || (bv1 == av1 && bi1 < ai1)) { o1 = bv1; oi = bi1; o2 = fminf(av1, bv2); }
        else { o1 = av1; oi = ai1; o2 = fminf(av2, bv1); }
        size_t o = (size_t)(m0 + tid) * NSA + blockIdx.y;
        gv1[o] = o1; gi1[o] = oi; gv2[o] = o2;
    }
}

// ---------------------------------------------------------------------------
// merge NSA slices -> tentative index; flag small-gap tokens
// ---------------------------------------------------------------------------
__global__ __launch_bounds__(256) void vq_merge(
        const float* __restrict__ gv1, const int* __restrict__ gi1,
        const float* __restrict__ gv2, int* __restrict__ idx_final,
        int* __restrict__ wl, int* __restrict__ count) {
    int t = blockIdx.x * 256 + threadIdx.x;
    float v1 = 3.4e38f, v2 = 3.4e38f; int i1 = 0x7fffffff;
#pragma unroll
    for (int s = 0; s < NSA; ++s) {
        size_t o = (size_t)t * NSA + s;
        float a1 = gv1[o]; int ai = gi1[o]; float a2 = gv2[o];
        if (a1 < v1 || (a1 == v1 && ai < i1)) { v2 = fminf(v1, a2); v1 = a1; i1 = ai; }
        else v2 = fminf(v2, a1);
    }
    idx_final[t] = i1;
    if (v2 - v1 < MARGIN1) {
        int p = atomicAdd(count, 1);
        wl[p] = t;
    }
}

// ---------------------------------------------------------------------------
// Tier-2: 3-pass f16 MFMA rescore over flagged (compacted) tokens.
// Grid (256, NST); block mb handles worklist rows [mb*128, mb*128+128),
// codes [by*256, by*256+256) as 2 n-tiles; inactive blocks exit.
// ---------------------------------------------------------------------------
__global__ __launch_bounds__(256, 2) void vq_rescore_mfma(
        const ushort_t* __restrict__ xh, const ushort_t* __restrict__ xl,
        const ushort_t* __restrict__ eh, const ushort_t* __restrict__ el,
        const float* __restrict__ e2, const int* __restrict__ wl,
        const int* __restrict__ count,
        float* __restrict__ rv, int* __restrict__ ri) {
    const int cnt = *count;
    const int m0 = blockIdx.x * 128;
    if (m0 >= cnt) return;
    __shared__ union U {
        struct { short A[128 * 32]; short B[128 * 32]; } t;
        struct { float v1[128][2]; int i1[128][2]; } r;
    } sh;
    const int tid = threadIdx.x;

    const int ca0 = tid, ca1 = 256 + tid;
    const int row0 = ca0 >> 2, gq0 = (ca0 & 3) ^ (row0 & 3);
    const int row1 = ca1 >> 2, gq1 = (ca1 & 3) ^ (row1 & 3);
    short* lA0 = &sh.t.A[ca0 * 8]; short* lA1 = &sh.t.A[ca1 * 8];
    short* lB0 = &sh.t.B[ca0 * 8]; short* lB1 = &sh.t.B[ca1 * 8];
    const int t0 = wl[min(m0 + row0, cnt - 1)];
    const int t1 = wl[min(m0 + row1, cnt - 1)];
    const size_t aoff0 = (size_t)t0 * DDIM + gq0 * 8;
    const size_t aoff1 = (size_t)t1 * DDIM + gq1 * 8;

    const int lane = tid & 63, wv = tid >> 6, wr = wv >> 1, wc = wv & 1;
    const int L15 = lane & 15, quad = lane >> 4;
    const int pqf = quad ^ (L15 & 3);
    const char* Abase = (const char*)sh.t.A + (size_t)(wr * 64 + L15) * 64 + pqf * 16;
    const char* Bbase = (const char*)sh.t.B + (size_t)(wc * 64 + L15) * 64 + pqf * 16;

    float v1[16]; int i1[16];
#pragma unroll
    for (int r2 = 0; r2 < 16; ++r2) { v1[r2] = 3.4e38f; i1[r2] = 0; }

#pragma unroll 1
    for (int nt = 0; nt < 2; ++nt) {
        const int n0 = blockIdx.y * 256 + nt * 128;
        const size_t boff0 = (size_t)(n0 + row0) * DDIM + gq0 * 8;
        const size_t boff1 = (size_t)(n0 + row1) * DDIM + gq1 * 8;
        f32x4 acc[4][4];
        // ph=0, kk=0 peel
        stage4(xh + aoff0, xh + aoff1, eh + boff0, eh + boff1, lA0, lA1, lB0, lB1, 0);
        __syncthreads();
        frag_mfma<true>(Abase, Bbase, acc);
        __syncthreads();
#pragma unroll 1
        for (int kk = 1; kk < 8; ++kk) {
            stage4(xh + aoff0, xh + aoff1, eh + boff0, eh + boff1, lA0, lA1, lB0, lB1, kk * 32);
            __syncthreads();
            frag_mfma<false>(Abase, Bbase, acc);
            __syncthreads();
        }
#pragma unroll 1
        for (int ph = 1; ph < 3; ++ph) {
            const ushort_t* As = (ph < 2) ? xh : xl;
            const ushort_t* Bs = (ph == 1) ? el : eh;
#pragma unroll 1
            for (int kk = 0; kk < 8; ++kk) {
                stage4(As + aoff0, As + aoff1, Bs + boff0, Bs + boff1, lA0, lA1, lB0, lB1, kk * 32);
                __syncthreads();
                frag_mfma<false>(Abase, Bbase, acc);
                __syncthreads();
            }
        }
        const int nb = n0 + wc * 64 + L15;
        float e2v[4];
#pragma unroll
        for (int j = 0; j < 4; ++j) e2v[j] = e2[nb + j * 16];
#pragma unroll
        for (int i = 0; i < 4; ++i)
#pragma unroll
            for (int r = 0; r < 4; ++r) {
                const int row = i * 4 + r;
#pragma unroll
                for (int j = 0; j < 4; ++j) {
                    float s = fmaf(-2.f, acc[i][j][r], e2v[j]);
                    int n = nb + j * 16;
                    if (s < v1[row]) { v1[row] = s; i1[row] = n; }
                }
            }
    }
    __syncthreads();
#pragma unroll
    for (int row = 0; row < 16; ++row) {
        float a1 = v1[row]; int ai = i1[row];
#pragma unroll
        for (int off = 1; off < 16; off <<= 1) {
            float o1 = __shfl_xor(a1, off, 64);
            int oi = __shfl_xor(ai, off, 64);
            if (o1 < a1 || (o1 == a1 && oi < ai)) { a1 = o1; ai = oi; }
        }
        if (L15 == 0) {
            int i = row >> 2, r = row & 3;
            int lr = wr * 64 + i * 16 + quad * 4 + r;
            sh.r.v1[lr][wc] = a1; sh.r.i1[lr][wc] = ai;
        }
    }
    __syncthreads();
    if (tid < 128 && m0 + tid < cnt) {
        float av1 = sh.r.v1[tid][0]; int ai1 = sh.r.i1[tid][0];
        float bv1 = sh.r.v1[tid][1]; int bi1 = sh.r.i1[tid][1];
        float o1; int oi;
        if (bv1 < av1 || (bv1 == av1 && bi1 < ai1)) { o1 = bv1; oi = bi1; }
        else { o1 = av1; oi = ai1; }
        size_t o = (size_t)(m0 + tid) * NST + blockIdx.y;
        rv[o] = o1; ri[o] = oi;
    }
}

// ---------------------------------------------------------------------------
// merge tier-2 slices for flagged tokens
// ---------------------------------------------------------------------------
__global__ __launch_bounds__(256) void vq_merge2(
        const int* __restrict__ wl, const int* __restrict__ count,
        const float* __restrict__ rv, const int* __restrict__ ri,
        int* __restrict__ idx_final) {
    int wi = blockIdx.x * 256 + threadIdx.x;
    if (wi >= *count) return;
    float v1 = 3.4e38f; int i1 = 0x7fffffff;
#pragma unroll
    for (int s = 0; s < NST; ++s) {
        size_t o = (size_t)wi * NST + s;
        float a = rv[o]; int ai = ri[o];
        if (a < v1 || (a == v1 && ai < i1)) { v1 = a; i1 = ai; }
    }
    idx_final[wl[wi]] = i1;
}

// ---------------------------------------------------------------------------
// gather: out[t][:] = embed[idx_final[t]][:]
// ---------------------------------------------------------------------------
__global__ __launch_bounds__(256) void vq_gather2(
        const float* __restrict__ embed, const int* __restrict__ idx_final,
        float* __restrict__ out) {
    int token = blockIdx.x * 4 + (threadIdx.x >> 6);
    int lane = threadIdx.x & 63;
    int idx = idx_final[token];
    const float4* src = (const float4*)(embed + (size_t)idx * DDIM);
    float4* dst = (float4*)(out + (size_t)token * DDIM);
    dst[lane] = src[lane];
}

// ===========================================================================
// Fallback fp32 path (round-1, validated) for small workspace
// ===========================================================================
#define TMF 128
#define DCF 32
#define LSF 132
#define KSPLITF 4
#define KPERF (KCB / KSPLITF)

__global__ __launch_bounds__(256) void vq_e2_fp32(const float* __restrict__ embed,
                                                  float* __restrict__ e2) {
    int k = blockIdx.x * blockDim.x + threadIdx.x;
    if (k >= KCB) return;
    const float4* row = (const float4*)(embed + (size_t)k * DDIM);
    float s = 0.f;
#pragma unroll
    for (int i = 0; i < DDIM / 4; ++i) {
        float4 v = row[i];
        s += v.x * v.x + v.y * v.y + v.z * v.z + v.w * v.w;
    }
    e2[k] = s;
}

__global__ __launch_bounds__(256, 3) void vq_main_fp32(
        const float* __restrict__ x, const float* __restrict__ embed,
        const float* __restrict__ e2,
        float* __restrict__ bestv, int* __restrict__ besti) {
    __shared__ union U {
        struct { float xs[DCF][LSF]; float es[DCF][LSF]; } t;
        struct { float v[TMF][16]; int i[TMF][16]; } r;
    } sh;
    const int tid = threadIdx.x;
    const int tx = tid & 15, ty = tid >> 4;
    const int m0 = blockIdx.x * TMF;
    const int kbase = blockIdx.y * KPERF;
    const int srow = tid >> 3, sd4 = (tid & 7) * 4;
    float bv[2][4]; int bi[2][4];
#pragma unroll
    for (int a = 0; a < 2; ++a)
#pragma unroll
        for (int b = 0; b < 4; ++b) { bv[a][b] = 3.4e38f; bi[a][b] = 0; }
    for (int kt = 0; kt < KPERF / 128; ++kt) {
        const int k0 = kbase + kt * 128;
        float acc[2][4][2][4];
#pragma unroll
        for (int a = 0; a < 2; ++a)
#pragma unroll
            for (int b = 0; b < 4; ++b)
#pragma unroll
                for (int c = 0; c < 2; ++c)
#pragma unroll
                    for (int e = 0; e < 4; ++e) acc[a][b][c][e] = 0.f;
        for (int dc = 0; dc < DDIM / DCF; ++dc) {
#pragma unroll
            for (int p = 0; p < 4; ++p) {
                int m = p * 32 + srow;
                float4 v = *(const float4*)(x + (size_t)(m0 + m) * DDIM + dc * DCF + sd4);
                sh.t.xs[sd4 + 0][m] = v.x; sh.t.xs[sd4 + 1][m] = v.y;
                sh.t.xs[sd4 + 2][m] = v.z; sh.t.xs[sd4 + 3][m] = v.w;
                float4 w = *(const float4*)(embed + (size_t)(k0 + m) * DDIM + dc * DCF + sd4);
                sh.t.es[sd4 + 0][m] = w.x; sh.t.es[sd4 + 1][m] = w.y;
                sh.t.es[sd4 + 2][m] = w.z; sh.t.es[sd4 + 3][m] = w.w;
            }
            __syncthreads();
#pragma unroll 8
            for (int d = 0; d < DCF; ++d) {
                float4 xa0 = *(const float4*)&sh.t.xs[d][ty * 4];
                float4 xa1 = *(const float4*)&sh.t.xs[d][ty * 4 + 64];
                float4 eb0 = *(const float4*)&sh.t.es[d][tx * 4];
                float4 eb1 = *(const float4*)&sh.t.es[d][tx * 4 + 64];
                float xr[2][4] = {{xa0.x, xa0.y, xa0.z, xa0.w}, {xa1.x, xa1.y, xa1.z, xa1.w}};
                float er[2][4] = {{eb0.x, eb0.y, eb0.z, eb0.w}, {eb1.x, eb1.y, eb1.z, eb1.w}};
#pragma unroll
                for (int a = 0; a < 2; ++a)
#pragma unroll
                    for (int b = 0; b < 4; ++b)
#pragma unroll
                        for (int c = 0; c < 2; ++c)
#pragma unroll
                            for (int e = 0; e < 4; ++e)
                                acc[a][b][c][e] += xr[a][b] * er[c][e];
            }
            __syncthreads();
        }
#pragma unroll
        for (int c = 0; c < 2; ++c)
#pragma unroll
            for (int e = 0; e < 4; ++e) {
                int k = k0 + c * 64 + tx * 4 + e;
                float ek = e2[k];
#pragma unroll
                for (int a = 0; a < 2; ++a)
#pragma unroll
                    for (int b = 0; b < 4; ++b) {
                        float s = ek - 2.f * acc[a][b][c][e];
                        if (s < bv[a][b]) { bv[a][b] = s; bi[a][b] = k; }
                    }
            }
    }
    __syncthreads();
#pragma unroll
    for (int a = 0; a < 2; ++a)
#pragma unroll
        for (int b = 0; b < 4; ++b) {
            int row = a * 64 + ty * 4 + b;
            sh.r.v[row][tx] = bv[a][b]; sh.r.i[row][tx] = bi[a][b];
        }
    __syncthreads();
    if (tid < TMF) {
        float best = sh.r.v[tid][0]; int idx = sh.r.i[tid][0];
#pragma unroll
        for (int j = 1; j < 16; ++j) {
            float v = sh.r.v[tid][j]; int ii = sh.r.i[tid][j];
            if (v < best || (v == best && ii < idx)) { best = v; idx = ii; }
        }
        bestv[(size_t)blockIdx.y * NTOK + m0 + tid] = best;
        besti[(size_t)blockIdx.y * NTOK + m0 + tid] = idx;
    }
}

__global__ __launch_bounds__(256) void vq_gather_fp32(
        const float* __restrict__ embed, const float* __restrict__ bestv,
        const int* __restrict__ besti, float* __restrict__ out) {
    int token = blockIdx.x * 4 + (threadIdx.x >> 6);
    int lane = threadIdx.x & 63;
    float best = bestv[token]; int idx = besti[token];
#pragma unroll
    for (int s = 1; s < KSPLITF; ++s) {
        float v = bestv[(size_t)s * NTOK + token];
        int ii = besti[(size_t)s * NTOK + token];
        if (v < best || (v == best && ii < idx)) { best = v; idx = ii; }
    }
    const float4* src = (const float4*)(embed + (size_t)idx * DDIM);
    float4* dst = (float4*)(out + (size_t)token * DDIM);
    dst[lane] = src[lane];
}

// ===========================================================================
extern "C" void kernel_launch(void* const* d_in, const int* in_sizes, int n_in,
                              void* d_out, int out_size, void* d_ws, size_t ws_size,
                              hipStream_t stream) {
    (void)in_sizes; (void)n_in; (void)out_size;
    const float* x = (const float*)d_in[0];
    const float* embed = (const float*)d_in[1];
    float* out = (float*)d_out;

    char* w = (char*)d_ws;
    auto carve = [&](size_t bytes) { char* p = w; w += (bytes + 255) & ~(size_t)255; return p; };

    const size_t sz_xh = (size_t)NTOK * DDIM * 2;
    const size_t sz_eh = (size_t)KCB * DDIM * 2;
    const size_t need = 2 * sz_xh + 2 * sz_eh + KCB * 4 +
                        3 * (size_t)NTOK * NSA * 4 + 2 * (size_t)NTOK * 4 +
                        2 * (size_t)NTOK * NST * 4 + 8192;

    if (ws_size >= need) {
        ushort_t* xh = (ushort_t*)carve(sz_xh);
        ushort_t* xl = (ushort_t*)carve(sz_xh);
        ushort_t* eh = (ushort_t*)carve(sz_eh);
        ushort_t* el = (ushort_t*)carve(sz_eh);
        float* e2 = (float*)carve(KCB * 4);
        float* gv1 = (float*)carve((size_t)NTOK * NSA * 4);
        int* gi1 = (int*)carve((size_t)NTOK * NSA * 4);
        float* gv2 = (float*)carve((size_t)NTOK * NSA * 4);
        int* idx_final = (int*)carve((size_t)NTOK * 4);
        int* wl = (int*)carve((size_t)NTOK * 4);
        float* rv = (float*)carve((size_t)NTOK * NST * 4);
        int* ri = (int*)carve((size_t)NTOK * NST * 4);
        int* count = (int*)carve(256);

        vq_convert_x<<<NTOK * DDIM / 4 / 256, 256, 0, stream>>>(x, xh, xl);
        vq_convert_e<<<KCB / 4, 256, 0, stream>>>(embed, eh, el, e2);
        hipMemsetAsync(count, 0, 4, stream);
        vq_pass_a<<<dim3(NTOK / 128, NSA), 256, 0, stream>>>(xh, eh, e2, gv1, gi1, gv2);
        vq_merge<<<NTOK / 256, 256, 0, stream>>>(gv1, gi1, gv2, idx_final, wl, count);
        vq_rescore_mfma<<<dim3(NTOK / 128, NST), 256, 0, stream>>>(
            xh, xl, eh, el, e2, wl, count, rv, ri);
        vq_merge2<<<NTOK / 256, 256, 0, stream>>>(wl, count, rv, ri, idx_final);
        vq_gather2<<<NTOK / 4, 256, 0, stream>>>(embed, idx_final, out);
    } else {
        float* e2 = (float*)carve(KCB * 4);
        float* bestv = (float*)carve((size_t)KSPLITF * NTOK * 4);
        int* besti = (int*)carve((size_t)KSPLITF * NTOK * 4);
        vq_e2_fp32<<<KCB / 256, 256, 0, stream>>>(embed, e2);
        vq_main_fp32<<<dim3(NTOK / TMF, KSPLITF), 256, 0, stream>>>(x, embed, e2, bestv, besti);
        vq_gather_fp32<<<NTOK / 4, 256, 0, stream>>>(embed, bestv, besti, out);
    }
}

// Round 4
// 249.099 us; speedup vs baseline: 5.0019x; 1.1316x over previous
//
#include <hip/hip_runtime.h>
#include <cstdint>

#define NTOK 32768
#define DDIM 256
#define KCB  4096
#define NSA 4            // n-splits in pass A (1024 codes per block)
#define NST 16           // n-splits in tier-2 (256 codes per block)
#define XCAP 16384       // max flagged tokens (safety cap; expect ~2%)
#define MARGIN_U 0.18f   // on u = dot - e2/2 + 512 scale (s-scale 0.36)

typedef _Float16 half8 __attribute__((ext_vector_type(8)));
typedef float f32x4 __attribute__((ext_vector_type(4)));
typedef unsigned short ushort_t;

// ---------------------------------------------------------------------------
// helpers
// ---------------------------------------------------------------------------
__device__ __forceinline__ ushort_t f2h(float f, float& back) {
    _Float16 h = (_Float16)f;
    back = (float)h;
    union { _Float16 h; ushort_t u; } c; c.h = h; return c.u;
}
__device__ __forceinline__ short h2s(_Float16 h) {
    union { _Float16 h; short s; } c; c.h = h; return c.s;
}
__device__ __forceinline__ void gload_lds16(const void* g, void* l) {
    __builtin_amdgcn_global_load_lds(
        (const __attribute__((address_space(1))) void*)g,
        (__attribute__((address_space(3))) void*)l, 16, 0, 0);
}
template <bool FIRST>
__device__ __forceinline__ void frag_mfma(const char* Ab, const char* Bb, f32x4 (&acc)[4][4]) {
    half8 af[4], bf[4];
#pragma unroll
    for (int i = 0; i < 4; ++i) af[i] = *(const half8*)(Ab + i * 1024);
#pragma unroll
    for (int j = 0; j < 4; ++j) bf[j] = *(const half8*)(Bb + j * 1024);
#pragma unroll
    for (int i = 0; i < 4; ++i)
#pragma unroll
        for (int j = 0; j < 4; ++j) {
            if (FIRST)
                acc[i][j] = __builtin_amdgcn_mfma_f32_16x16x32_f16(
                    af[i], bf[j], (f32x4){0.f, 0.f, 0.f, 0.f}, 0, 0, 0);
            else
                acc[i][j] = __builtin_amdgcn_mfma_f32_16x16x32_f16(
                    af[i], bf[j], acc[i][j], 0, 0, 0);
        }
}
__device__ __forceinline__ void stage4(const ushort_t* a0, const ushort_t* a1,
                                       const ushort_t* b0, const ushort_t* b1,
                                       short* lA0, short* lA1, short* lB0, short* lB1,
                                       int koff) {
    gload_lds16(a0 + koff, lA0);
    gload_lds16(a1 + koff, lA1);
    gload_lds16(b0 + koff, lB0);
    gload_lds16(b1 + koff, lB1);
}

// ---------------------------------------------------------------------------
// convert embed -> f16 hi/lo + cc[k] = 512 - 0.5*e2[k]  (wave per row)
// ---------------------------------------------------------------------------
__global__ __launch_bounds__(256) void vq_convert_e(
        const float* __restrict__ embed, ushort_t* __restrict__ hi,
        ushort_t* __restrict__ lo, float* __restrict__ cc) {
    int row = blockIdx.x * 4 + (threadIdx.x >> 6);
    int lane = threadIdx.x & 63;
    size_t off = (size_t)row * DDIM + lane * 4;
    float4 v = *(const float4*)(embed + off);
    float bx, by, bz, bw;
    ushort4 h, l;
    h.x = f2h(v.x, bx); h.y = f2h(v.y, by); h.z = f2h(v.z, bz); h.w = f2h(v.w, bw);
    float t;
    l.x = f2h(v.x - bx, t); l.y = f2h(v.y - by, t);
    l.z = f2h(v.z - bz, t); l.w = f2h(v.w - bw, t);
    *(ushort4*)(hi + off) = h;
    *(ushort4*)(lo + off) = l;
    float s = v.x * v.x + v.y * v.y + v.z * v.z + v.w * v.w;
#pragma unroll
    for (int o = 1; o < 64; o <<= 1) s += __shfl_xor(s, o, 64);
    if (lane == 0) cc[row] = 512.f - 0.5f * s;
}

// ---------------------------------------------------------------------------
// Pass A: 128 tokens x 1024 codes. A (x->f16) staged ONCE into LDS; B (eh)
// double-buffered, single barrier per k-iter. Epilogue: packed-index top-2
// maximization of u = dot + cc  (4 VALU ops per score).
// ---------------------------------------------------------------------------
__global__ __launch_bounds__(256, 2) void vq_pass_a(
        const float* __restrict__ x, const ushort_t* __restrict__ eh,
        const float* __restrict__ cc,
        float* __restrict__ gv1, int* __restrict__ gi1, float* __restrict__ gv2) {
    __shared__ union U {
        struct { short A[8][128][32]; short B[2][128][32]; } t;  // 64KB + 16KB
        struct { float v1[128][2]; int i1[128][2]; float v2[128][2]; } r;
    } sh;
    const int tid = threadIdx.x;
    const int m0 = blockIdx.x * 128;
    const int kbase = blockIdx.y * (KCB / NSA);

    const int lane = tid & 63, wv = tid >> 6, wr = wv >> 1, wc = wv & 1;
    const int L15 = lane & 15, quad = lane >> 4;

    const int ca0 = tid, ca1 = 256 + tid;
    const int row0 = ca0 >> 2, q0 = ca0 & 3;
    const int row1 = ca1 >> 2, q1 = ca1 & 3;
    short* lB0 = &sh.t.B[0][0][0];
    short* lB1 = &sh.t.B[1][0][0];

    auto stageB = [&](int it) {
        int nt = it >> 3, kk = it & 7;
        short* dst = (it & 1) ? lB1 : lB0;
        int n0 = kbase + nt * 128;
        gload_lds16(eh + (size_t)(n0 + row0) * DDIM + kk * 32 + q0 * 8, dst + ca0 * 8);
        gload_lds16(eh + (size_t)(n0 + row1) * DDIM + kk * 32 + q1 * 8, dst + ca1 * 8);
    };

    stageB(0);

    // ---- stage A: x fp32 -> f16, once per block ----
    {
        const int fr = tid >> 6;      // row offset 0..3
        const int f = tid & 63;       // float4 index within row
        const int akk = f >> 3, aoff = (f & 7) * 4;
#pragma unroll 4
        for (int s = 0; s < 32; ++s) {
            int row = s * 4 + fr;
            float4 v = *(const float4*)(x + (size_t)(m0 + row) * DDIM + f * 4);
            short4 pk = { h2s((_Float16)v.x), h2s((_Float16)v.y),
                          h2s((_Float16)v.z), h2s((_Float16)v.w) };
            *(short4*)(&sh.t.A[akk][row][aoff]) = pk;
        }
    }

    const char* Ab0 = (const char*)&sh.t.A[0][0][0] + (size_t)(wr * 64 + L15) * 64 + quad * 16;
    const char* Bb0 = (const char*)lB0 + (size_t)(wc * 64 + L15) * 64 + quad * 16;

    float v1p[16], v2p[16];
#pragma unroll
    for (int s = 0; s < 16; ++s) { v1p[s] = -3.4e38f; v2p[s] = -3.4e38f; }

#pragma unroll 1
    for (int nt = 0; nt < 8; ++nt) {
        f32x4 acc[4][4];
        float cc0, cc1, cc2, cc3;
#pragma unroll
        for (int kk = 0; kk < 8; ++kk) {
            const int it = nt * 8 + kk;
            __syncthreads();
            if (it + 1 < 64) stageB(it + 1);
            if (kk == 1) {   // prefetch cc, consumed at epilogue (7 iters later)
                const float* cb = cc + kbase + nt * 128 + wc * 64 + L15;
                cc0 = cb[0]; cc1 = cb[16]; cc2 = cb[32]; cc3 = cb[48];
            }
            const char* Ab = Ab0 + kk * 8192;
            const char* Bb = Bb0 + (it & 1) * 8192;
            if (kk == 0) frag_mfma<true>(Ab, Bb, acc);
            else         frag_mfma<false>(Ab, Bb, acc);
        }
        // packed top-2 epilogue (maximize u)
#pragma unroll
        for (int i = 0; i < 4; ++i)
#pragma unroll
            for (int r = 0; r < 4; ++r) {
                const int slot = i * 4 + r;
#pragma unroll
                for (int j = 0; j < 4; ++j) {
                    float ccj = (j == 0) ? cc0 : (j == 1) ? cc1 : (j == 2) ? cc2 : cc3;
                    float u = acc[i][j][r] + ccj;
                    unsigned linv = 31u - (unsigned)(nt * 4 + j);
                    float p = __uint_as_float((__float_as_uint(u) & ~31u) | linv);
                    float tmin = fminf(v1p[slot], p);
                    v1p[slot] = fmaxf(v1p[slot], p);
                    v2p[slot] = fmaxf(v2p[slot], tmin);
                }
            }
    }

    __syncthreads();
    // unpack + cross-lane butterfly + cross-wc merge
#pragma unroll
    for (int i = 0; i < 4; ++i)
#pragma unroll
        for (int r = 0; r < 4; ++r) {
            const int slot = i * 4 + r;
            unsigned b1 = __float_as_uint(v1p[slot]);
            int l1 = 31 - (int)(b1 & 31u);
            float a1 = v1p[slot];
            int ai = kbase + (l1 >> 2) * 128 + wc * 64 + (l1 & 3) * 16 + L15;
            float a2 = v2p[slot];
#pragma unroll
            for (int off = 1; off < 16; off <<= 1) {
                float o1 = __shfl_xor(a1, off, 64);
                int oi = __shfl_xor(ai, off, 64);
                float o2 = __shfl_xor(a2, off, 64);
                if (o1 > a1 || (o1 == a1 && oi < ai)) {
                    a2 = fmaxf(a1, o2); a1 = o1; ai = oi;
                } else {
                    a2 = fmaxf(a2, o1);
                }
            }
            if (L15 == 0) {
                int lr = wr * 64 + i * 16 + quad * 4 + r;
                sh.r.v1[lr][wc] = a1; sh.r.i1[lr][wc] = ai; sh.r.v2[lr][wc] = a2;
            }
        }
    __syncthreads();
    if (tid < 128) {
        float av1 = sh.r.v1[tid][0]; int ai1 = sh.r.i1[tid][0]; float av2 = sh.r.v2[tid][0];
        float bv1 = sh.r.v1[tid][1]; int bi1 = sh.r.i1[tid][1]; float bv2 = sh.r.v2[tid][1];
        float o1, o2; int oi;
        if (bv1 > av1 || (bv1 == av1 && bi1 < ai1)) { o1 = bv1; oi = bi1; o2 = fmaxf(av1, bv2); }
        else { o1 = av1; oi = ai1; o2 = fmaxf(av2, bv1); }
        size_t o = (size_t)(m0 + tid) * NSA + blockIdx.y;
        gv1[o] = o1; gi1[o] = oi; gv2[o] = o2;
    }
}

// ---------------------------------------------------------------------------
// merge NSA slices per token; gather clear winners; flag small-gap tokens
// (one wave per token)
// ---------------------------------------------------------------------------
__global__ __launch_bounds__(256) void vq_merge_gather(
        const float* __restrict__ gv1, const int* __restrict__ gi1,
        const float* __restrict__ gv2, const float* __restrict__ embed,
        float* __restrict__ out, int* __restrict__ wl, int* __restrict__ count) {
    int wave = threadIdx.x >> 6, lane = threadIdx.x & 63;
    int t = blockIdx.x * 4 + wave;
    float v1 = -3.4e38f, v2 = -3.4e38f; int i1 = 0x7fffffff;
    if (lane < NSA) {
        size_t o = (size_t)t * NSA + lane;
        v1 = gv1[o]; i1 = gi1[o]; v2 = gv2[o];
    }
#pragma unroll
    for (int off = 1; off < NSA; off <<= 1) {
        float o1 = __shfl_xor(v1, off, 64);
        int oi = __shfl_xor(i1, off, 64);
        float o2 = __shfl_xor(v2, off, 64);
        if (o1 > v1 || (o1 == v1 && oi < i1)) { v2 = fmaxf(v1, o2); v1 = o1; i1 = oi; }
        else v2 = fmaxf(v2, o1);
    }
    int flag = __shfl((v1 - v2 < MARGIN_U) ? 1 : 0, 0, 64);
    int idx = __shfl(i1, 0, 64);
    int p = 0x7fffffff;
    if (flag && lane == 0) p = atomicAdd(count, 1);
    p = __shfl(p, 0, 64);
    if (flag && p < XCAP) {
        if (lane == 0) wl[p] = t;
    } else {
        const float4* src = (const float4*)(embed + (size_t)idx * DDIM);
        float4* dst = (float4*)(out + (size_t)t * DDIM);
        dst[lane] = src[lane];
    }
}

// ---------------------------------------------------------------------------
// compact flagged tokens: x -> f16 hi/lo, contiguous rows (one wave per token)
// ---------------------------------------------------------------------------
__global__ __launch_bounds__(256) void vq_convert_flagged(
        const float* __restrict__ x, const int* __restrict__ wl,
        const int* __restrict__ count,
        ushort_t* __restrict__ xhc, ushort_t* __restrict__ xlc) {
    int wave = threadIdx.x >> 6, lane = threadIdx.x & 63;
    int wi = blockIdx.x * 4 + wave;
    int cnt = min(*count, XCAP);
    if (wi >= cnt) return;
    int t = wl[wi];
    float4 v = *(const float4*)(x + (size_t)t * DDIM + lane * 4);
    float bx, by, bz, bw;
    ushort4 h, l;
    h.x = f2h(v.x, bx); h.y = f2h(v.y, by); h.z = f2h(v.z, bz); h.w = f2h(v.w, bw);
    float tt;
    l.x = f2h(v.x - bx, tt); l.y = f2h(v.y - by, tt);
    l.z = f2h(v.z - bz, tt); l.w = f2h(v.w - bw, tt);
    size_t off = (size_t)wi * DDIM + lane * 4;
    *(ushort4*)(xhc + off) = h;
    *(ushort4*)(xlc + off) = l;
}

// ---------------------------------------------------------------------------
// Tier-2: 3-pass f16 MFMA rescore over compacted flagged tokens.
// Grid (XCAP/128, NST). Maximize u = 3-pass dot + cc.
// ---------------------------------------------------------------------------
__global__ __launch_bounds__(256, 2) void vq_rescore_mfma(
        const ushort_t* __restrict__ xhc, const ushort_t* __restrict__ xlc,
        const ushort_t* __restrict__ eh, const ushort_t* __restrict__ el,
        const float* __restrict__ cc, const int* __restrict__ count,
        float* __restrict__ rv, int* __restrict__ ri) {
    const int cnt = min(*count, XCAP);
    const int m0 = blockIdx.x * 128;
    if (m0 >= cnt) return;
    __shared__ union U {
        struct { short A[128 * 32]; short B[128 * 32]; } t;
        struct { float v1[128][2]; int i1[128][2]; } r;
    } sh;
    const int tid = threadIdx.x;

    const int ca0 = tid, ca1 = 256 + tid;
    const int row0 = ca0 >> 2, gq0 = (ca0 & 3) ^ (row0 & 3);
    const int row1 = ca1 >> 2, gq1 = (ca1 & 3) ^ (row1 & 3);
    short* lA0 = &sh.t.A[ca0 * 8]; short* lA1 = &sh.t.A[ca1 * 8];
    short* lB0 = &sh.t.B[ca0 * 8]; short* lB1 = &sh.t.B[ca1 * 8];
    const size_t aoff0 = (size_t)min(m0 + row0, cnt - 1) * DDIM + gq0 * 8;
    const size_t aoff1 = (size_t)min(m0 + row1, cnt - 1) * DDIM + gq1 * 8;

    const int lane = tid & 63, wv = tid >> 6, wr = wv >> 1, wc = wv & 1;
    const int L15 = lane & 15, quad = lane >> 4;
    const int pqf = quad ^ (L15 & 3);
    const char* Abase = (const char*)sh.t.A + (size_t)(wr * 64 + L15) * 64 + pqf * 16;
    const char* Bbase = (const char*)sh.t.B + (size_t)(wc * 64 + L15) * 64 + pqf * 16;

    float v1[16]; int i1[16];
#pragma unroll
    for (int r2 = 0; r2 < 16; ++r2) { v1[r2] = -3.4e38f; i1[r2] = 0; }

#pragma unroll 1
    for (int nt = 0; nt < 2; ++nt) {
        const int n0 = blockIdx.y * 256 + nt * 128;
        const size_t boff0 = (size_t)(n0 + row0) * DDIM + gq0 * 8;
        const size_t boff1 = (size_t)(n0 + row1) * DDIM + gq1 * 8;
        f32x4 acc[4][4];
        stage4(xhc + aoff0, xhc + aoff1, eh + boff0, eh + boff1, lA0, lA1, lB0, lB1, 0);
        __syncthreads();
        frag_mfma<true>(Abase, Bbase, acc);
        __syncthreads();
#pragma unroll 1
        for (int kk = 1; kk < 8; ++kk) {
            stage4(xhc + aoff0, xhc + aoff1, eh + boff0, eh + boff1, lA0, lA1, lB0, lB1, kk * 32);
            __syncthreads();
            frag_mfma<false>(Abase, Bbase, acc);
            __syncthreads();
        }
#pragma unroll 1
        for (int ph = 1; ph < 3; ++ph) {
            const ushort_t* As = (ph < 2) ? xhc : xlc;
            const ushort_t* Bs = (ph == 1) ? el : eh;
#pragma unroll 1
            for (int kk = 0; kk < 8; ++kk) {
                stage4(As + aoff0, As + aoff1, Bs + boff0, Bs + boff1, lA0, lA1, lB0, lB1, kk * 32);
                __syncthreads();
                frag_mfma<false>(Abase, Bbase, acc);
                __syncthreads();
            }
        }
        const int nb = n0 + wc * 64 + L15;
        float ccv[4];
#pragma unroll
        for (int j = 0; j < 4; ++j) ccv[j] = cc[nb + j * 16];
#pragma unroll
        for (int i = 0; i < 4; ++i)
#pragma unroll
            for (int r = 0; r < 4; ++r) {
                const int row = i * 4 + r;
#pragma unroll
                for (int j = 0; j < 4; ++j) {
                    float u = acc[i][j][r] + ccv[j];
                    int n = nb + j * 16;
                    if (u > v1[row]) { v1[row] = u; i1[row] = n; }
                }
            }
    }
    __syncthreads();
#pragma unroll
    for (int row = 0; row < 16; ++row) {
        float a1 = v1[row]; int ai = i1[row];
#pragma unroll
        for (int off = 1; off < 16; off <<= 1) {
            float o1 = __shfl_xor(a1, off, 64);
            int oi = __shfl_xor(ai, off, 64);
            if (o1 > a1 || (o1 == a1 && oi < ai)) { a1 = o1; ai = oi; }
        }
        if (L15 == 0) {
            int i = row >> 2, r = row & 3;
            int lr = wr * 64 + i * 16 + quad * 4 + r;
            sh.r.v1[lr][wc] = a1; sh.r.i1[lr][wc] = ai;
        }
    }
    __syncthreads();
    if (tid < 128 && m0 + tid < cnt) {
        float av1 = sh.r.v1[tid][0]; int ai1 = sh.r.i1[tid][0];
        float bv1 = sh.r.v1[tid][1]; int bi1 = sh.r.i1[tid][1];
        float o1; int oi;
        if (bv1 > av1 || (bv1 == av1 && bi1 < ai1)) { o1 = bv1; oi = bi1; }
        else { o1 = av1; oi = ai1; }
        size_t o = (size_t)(m0 + tid) * NST + blockIdx.y;
        rv[o] = o1; ri[o] = oi;
    }
}

// ---------------------------------------------------------------------------
// merge tier-2 slices + gather for flagged tokens (one wave per token)
// ---------------------------------------------------------------------------
__global__ __launch_bounds__(256) void vq_merge2_gather(
        const int* __restrict__ wl, const int* __restrict__ count,
        const float* __restrict__ rv, const int* __restrict__ ri,
        const float* __restrict__ embed, float* __restrict__ out) {
    int wave = threadIdx.x >> 6, lane = threadIdx.x & 63;
    int wi = blockIdx.x * 4 + wave;
    int cnt = min(*count, XCAP);
    if (wi >= cnt) return;
    float v1 = -3.4e38f; int i1 = 0x7fffffff;
    if (lane < NST) {
        size_t o = (size_t)wi * NST + lane;
        v1 = rv[o]; i1 = ri[o];
    }
#pragma unroll
    for (int off = 1; off < NST; off <<= 1) {
        float o1 = __shfl_xor(v1, off, 64);
        int oi = __shfl_xor(i1, off, 64);
        if (o1 > v1 || (o1 == v1 && oi < i1)) { v1 = o1; i1 = oi; }
    }
    int idx = __shfl(i1, 0, 64);
    int t = wl[wi];
    const float4* src = (const float4*)(embed + (size_t)idx * DDIM);
    float4* dst = (float4*)(out + (size_t)t * DDIM);
    dst[lane] = src[lane];
}

// ===========================================================================
// Fallback fp32 path (round-1, validated) for small workspace
// ===========================================================================
#define TMF 128
#define DCF 32
#define LSF 132
#define KSPLITF 4
#define KPERF (KCB / KSPLITF)

__global__ __launch_bounds__(256) void vq_e2_fp32(const float* __restrict__ embed,
                                                  float* __restrict__ e2) {
    int k = blockIdx.x * blockDim.x + threadIdx.x;
    if (k >= KCB) return;
    const float4* row = (const float4*)(embed + (size_t)k * DDIM);
    float s = 0.f;
#pragma unroll
    for (int i = 0; i < DDIM / 4; ++i) {
        float4 v = row[i];
        s += v.x * v.x + v.y * v.y + v.z * v.z + v.w * v.w;
    }
    e2[k] = s;
}

__global__ __launch_bounds__(256, 3) void vq_main_fp32(
        const float* __restrict__ x, const float* __restrict__ embed,
        const float* __restrict__ e2,
        float* __restrict__ bestv, int* __restrict__ besti) {
    __shared__ union U {
        struct { float xs[DCF][LSF]; float es[DCF][LSF]; } t;
        struct { float v[TMF][16]; int i[TMF][16]; } r;
    } sh;
    const int tid = threadIdx.x;
    const int tx = tid & 15, ty = tid >> 4;
    const int m0 = blockIdx.x * TMF;
    const int kbase = blockIdx.y * KPERF;
    const int srow = tid >> 3, sd4 = (tid & 7) * 4;
    float bv[2][4]; int bi[2][4];
#pragma unroll
    for (int a = 0; a < 2; ++a)
#pragma unroll
        for (int b = 0; b < 4; ++b) { bv[a][b] = 3.4e38f; bi[a][b] = 0; }
    for (int kt = 0; kt < KPERF / 128; ++kt) {
        const int k0 = kbase + kt * 128;
        float acc[2][4][2][4];
#pragma unroll
        for (int a = 0; a < 2; ++a)
#pragma unroll
            for (int b = 0; b < 4; ++b)
#pragma unroll
                for (int c = 0; c < 2; ++c)
#pragma unroll
                    for (int e = 0; e < 4; ++e) acc[a][b][c][e] = 0.f;
        for (int dc = 0; dc < DDIM / DCF; ++dc) {
#pragma unroll
            for (int p = 0; p < 4; ++p) {
                int m = p * 32 + srow;
                float4 v = *(const float4*)(x + (size_t)(m0 + m) * DDIM + dc * DCF + sd4);
                sh.t.xs[sd4 + 0][m] = v.x; sh.t.xs[sd4 + 1][m] = v.y;
                sh.t.xs[sd4 + 2][m] = v.z; sh.t.xs[sd4 + 3][m] = v.w;
                float4 w = *(const float4*)(embed + (size_t)(k0 + m) * DDIM + dc * DCF + sd4);
                sh.t.es[sd4 + 0][m] = w.x; sh.t.es[sd4 + 1][m] = w.y;
                sh.t.es[sd4 + 2][m] = w.z; sh.t.es[sd4 + 3][m] = w.w;
            }
            __syncthreads();
#pragma unroll 8
            for (int d = 0; d < DCF; ++d) {
                float4 xa0 = *(const float4*)&sh.t.xs[d][ty * 4];
                float4 xa1 = *(const float4*)&sh.t.xs[d][ty * 4 + 64];
                float4 eb0 = *(const float4*)&sh.t.es[d][tx * 4];
                float4 eb1 = *(const float4*)&sh.t.es[d][tx * 4 + 64];
                float xr[2][4] = {{xa0.x, xa0.y, xa0.z, xa0.w}, {xa1.x, xa1.y, xa1.z, xa1.w}};
                float er[2][4] = {{eb0.x, eb0.y, eb0.z, eb0.w}, {eb1.x, eb1.y, eb1.z, eb1.w}};
#pragma unroll
                for (int a = 0; a < 2; ++a)
#pragma unroll
                    for (int b = 0; b < 4; ++b)
#pragma unroll
                        for (int c = 0; c < 2; ++c)
#pragma unroll
                            for (int e = 0; e < 4; ++e)
                                acc[a][b][c][e] += xr[a][b] * er[c][e];
            }
            __syncthreads();
        }
#pragma unroll
        for (int c = 0; c < 2; ++c)
#pragma unroll
            for (int e = 0; e < 4; ++e) {
                int k = k0 + c * 64 + tx * 4 + e;
                float ek = e2[k];
#pragma unroll
                for (int a = 0; a < 2; ++a)
#pragma unroll
                    for (int b = 0; b < 4; ++b) {
                        float s = ek - 2.f * acc[a][b][c][e];
                        if (s < bv[a][b]) { bv[a][b] = s; bi[a][b] = k; }
                    }
            }
    }
    __syncthreads();
#pragma unroll
    for (int a = 0; a < 2; ++a)
#pragma unroll
        for (int b = 0; b < 4; ++b) {
            int row = a * 64 + ty * 4 + b;
            sh.r.v[row][tx] = bv[a][b]; sh.r.i[row][tx] = bi[a][b];
        }
    __syncthreads();
    if (tid < TMF) {
        float best = sh.r.v[tid][0]; int idx = sh.r.i[tid][0];
#pragma unroll
        for (int j = 1; j < 16; ++j) {
            float v = sh.r.v[tid][j]; int ii = sh.r.i[tid][j];
            if (v < best || (v == best && ii < idx)) { best = v; idx = ii; }
        }
        bestv[(size_t)blockIdx.y * NTOK + m0 + tid] = best;
        besti[(size_t)blockIdx.y * NTOK + m0 + tid] = idx;
    }
}

__global__ __launch_bounds__(256) void vq_gather_fp32(
        const float* __restrict__ embed, const float* __restrict__ bestv,
        const int* __restrict__ besti, float* __restrict__ out) {
    int token = blockIdx.x * 4 + (threadIdx.x >> 6);
    int lane = threadIdx.x & 63;
    float best = bestv[token]; int idx = besti[token];
#pragma unroll
    for (int s = 1; s < KSPLITF; ++s) {
        float v = bestv[(size_t)s * NTOK + token];
        int ii = besti[(size_t)s * NTOK + token];
        if (v < best || (v == best && ii < idx)) { best = v; idx = ii; }
    }
    const float4* src = (const float4*)(embed + (size_t)idx * DDIM);
    float4* dst = (float4*)(out + (size_t)token * DDIM);
    dst[lane] = src[lane];
}

// ===========================================================================
extern "C" void kernel_launch(void* const* d_in, const int* in_sizes, int n_in,
                              void* d_out, int out_size, void* d_ws, size_t ws_size,
                              hipStream_t stream) {
    (void)in_sizes; (void)n_in; (void)out_size;
    const float* x = (const float*)d_in[0];
    const float* embed = (const float*)d_in[1];
    float* out = (float*)d_out;

    char* w = (char*)d_ws;
    auto carve = [&](size_t bytes) { char* p = w; w += (bytes + 255) & ~(size_t)255; return p; };

    const size_t sz_eh = (size_t)KCB * DDIM * 2;           // 2 MB
    const size_t sz_xc = (size_t)XCAP * DDIM * 2;          // 8 MB
    const size_t need = 2 * sz_eh + KCB * 4 + 3 * (size_t)NTOK * NSA * 4 +
                        (size_t)XCAP * 4 + 2 * sz_xc + 2 * (size_t)XCAP * NST * 4 + 8192;

    if (ws_size >= need) {
        ushort_t* eh = (ushort_t*)carve(sz_eh);
        ushort_t* el = (ushort_t*)carve(sz_eh);
        float* cc = (float*)carve(KCB * 4);
        float* gv1 = (float*)carve((size_t)NTOK * NSA * 4);
        int* gi1 = (int*)carve((size_t)NTOK * NSA * 4);
        float* gv2 = (float*)carve((size_t)NTOK * NSA * 4);
        int* wl = (int*)carve((size_t)XCAP * 4);
        ushort_t* xhc = (ushort_t*)carve(sz_xc);
        ushort_t* xlc = (ushort_t*)carve(sz_xc);
        float* rv = (float*)carve((size_t)XCAP * NST * 4);
        int* ri = (int*)carve((size_t)XCAP * NST * 4);
        int* count = (int*)carve(256);

        vq_convert_e<<<KCB / 4, 256, 0, stream>>>(embed, eh, el, cc);
        hipMemsetAsync(count, 0, 4, stream);
        vq_pass_a<<<dim3(NTOK / 128, NSA), 256, 0, stream>>>(x, eh, cc, gv1, gi1, gv2);
        vq_merge_gather<<<NTOK / 4, 256, 0, stream>>>(gv1, gi1, gv2, embed, out, wl, count);
        vq_convert_flagged<<<XCAP / 4, 256, 0, stream>>>(x, wl, count, xhc, xlc);
        vq_rescore_mfma<<<dim3(XCAP / 128, NST), 256, 0, stream>>>(
            xhc, xlc, eh, el, cc, count, rv, ri);
        vq_merge2_gather<<<XCAP / 4, 256, 0, stream>>>(wl, count, rv, ri, embed, out);
    } else {
        float* e2 = (float*)carve(KCB * 4);
        float* bestv = (float*)carve((size_t)KSPLITF * NTOK * 4);
        int* besti = (int*)carve((size_t)KSPLITF * NTOK * 4);
        vq_e2_fp32<<<KCB / 256, 256, 0, stream>>>(embed, e2);
        vq_main_fp32<<<dim3(NTOK / TMF, KSPLITF), 256, 0, stream>>>(x, embed, e2, bestv, besti);
        vq_gather_fp32<<<NTOK / 4, 256, 0, stream>>>(embed, bestv, besti, out);
    }
}